// Round 20
// baseline (92.080 us; speedup 1.0000x reference)
//
#include <hip/hip_runtime.h>
#include <math.h>

#define NX 128
#define NY 128
#define NZ 64
#define NVOX (NX * NY * NZ)   // 1048576 = 1<<20
#define NC 32
#define FH 120
#define FW 160
#define FHW (FH * FW)         // 19200
#define VOXSZ 0.04f
#define NB 2
#define IDX_BYTES ((size_t)NB * NVOX * 4)     // 8 MB
#define T_BYTES ((size_t)NB * FHW * NC * 4)   // 4.9 MB (fallback path)

// ---------- Kernel A: projection -> packed idx (-1 invalid) + valid plane ----
// Projection = PINNED R14 pipeline (f32, contract off, pairwise association,
// IEEE f32 divide, __float2int_rn) -- bit-exact vs harness reference.
__global__ __launch_bounds__(256) void project_kernel(
    const float* __restrict__ proj,
    const float* __restrict__ origin,
    int* __restrict__ idxbuf,
    float* __restrict__ out)
{
#pragma clang fp contract(off)
    const int tid = blockIdx.x * 256 + threadIdx.x;
    const int b = tid >> 20;
    const int n = tid & (NVOX - 1);
    const int i = n >> 13;
    const int j = (n >> 6) & (NY - 1);
    const int k = n & (NZ - 1);

    const float* P = proj + b * 12;
    const float ox = origin[b * 3 + 0];
    const float oy = origin[b * 3 + 1];
    const float oz = origin[b * 3 + 2];

    const float wx = (float)i * VOXSZ + ox;
    const float wy = (float)j * VOXSZ + oy;
    const float wz = (float)k * VOXSZ + oz;

    const float tx = P[0] * wx + P[1] * wy;
    const float ty = P[4] * wx + P[5] * wy;
    const float tz = P[8] * wx + P[9] * wy;

    const float cx = tx + (P[2]  * wz + P[3]);
    const float cy = ty + (P[6]  * wz + P[7]);
    const float cz = tz + (P[10] * wz + P[11]);

    const float qx = cx / cz;
    const float qy = cy / cz;
    const int px = __float2int_rn(qx);
    const int py = __float2int_rn(qy);
    const bool v = (px >= 0) & (py >= 0) & (px < FW) & (py < FH) & (cz > 0.0f);

    idxbuf[tid] = v ? (py * FW + px) : -1;
    out[(size_t)NB * NC * NVOX + (size_t)b * NVOX + n] = v ? 1.0f : 0.0f;
}

// ---------- Kernel B: channel-parallel gather + streaming float4 stores -----
// One thread per (b, c, 4 consecutive voxels). Single feat plane per thread;
// consecutive threads -> same plane, near-identical idx (L1 reuse), stores
// 16B contiguous (4KB per wave instruction) = fill-kernel access shape.
__global__ __launch_bounds__(256) void scatter_kernel(
    const float* __restrict__ feat,
    const int* __restrict__ idxbuf,
    float* __restrict__ out)
{
    const int tid = blockIdx.x * 256 + threadIdx.x;   // 16,777,216 total
    const int n4 = tid & ((NVOX >> 2) - 1);           // 18 bits
    const int c  = (tid >> 18) & (NC - 1);
    const int b  = tid >> 23;
    const int n0 = n4 * 4;

    const int4 id4 = *(const int4*)(idxbuf + (size_t)b * NVOX + n0);
    const float* fp = feat + ((size_t)b * NC + c) * FHW;

    float4 r;
    r.x = (id4.x >= 0) ? fp[id4.x] : 0.0f;
    r.y = (id4.y >= 0) ? fp[id4.y] : 0.0f;
    r.z = (id4.z >= 0) ? fp[id4.z] : 0.0f;
    r.w = (id4.w >= 0) ? fp[id4.w] : 0.0f;

    *(float4*)(out + ((size_t)b * NC + c) * NVOX + n0) = r;
}

// ---------- Fallback (R18): transpose + per-voxel kernel ---------------------
__global__ __launch_bounds__(256) void transpose_feat_kernel(
    const float* __restrict__ feat, float* __restrict__ T)
{
    const int t = blockIdx.x * 256 + threadIdx.x;
    const int b = t / FHW;
    const int pix = t - b * FHW;
    const float* fb = feat + (size_t)b * NC * FHW + pix;
    float v[NC];
    #pragma unroll
    for (int c = 0; c < NC; ++c) v[c] = fb[(size_t)c * FHW];
    float4* row = (float4*)(T + ((size_t)b * FHW + pix) * NC);
    #pragma unroll
    for (int r = 0; r < NC / 4; ++r)
        row[r] = make_float4(v[4*r], v[4*r+1], v[4*r+2], v[4*r+3]);
}

__global__ __launch_bounds__(256) void voxel_backproject_kernel(
    const float* __restrict__ proj,
    const float* __restrict__ T,
    const float* __restrict__ origin,
    float* __restrict__ out)
{
#pragma clang fp contract(off)
    const int tid = blockIdx.x * 256 + threadIdx.x;
    const int b = tid >> 20;
    const int n = tid & (NVOX - 1);
    const int i = n >> 13;
    const int j = (n >> 6) & (NY - 1);
    const int k = n & (NZ - 1);

    const float* P = proj + b * 12;
    const float ox = origin[b * 3 + 0];
    const float oy = origin[b * 3 + 1];
    const float oz = origin[b * 3 + 2];
    const float wx = (float)i * VOXSZ + ox;
    const float wy = (float)j * VOXSZ + oy;
    const float wz = (float)k * VOXSZ + oz;
    const float tx = P[0] * wx + P[1] * wy;
    const float ty = P[4] * wx + P[5] * wy;
    const float tz = P[8] * wx + P[9] * wy;
    const float cx = tx + (P[2]  * wz + P[3]);
    const float cy = ty + (P[6]  * wz + P[7]);
    const float cz = tz + (P[10] * wz + P[11]);
    const float qx = cx / cz;
    const float qy = cy / cz;
    const int px = __float2int_rn(qx);
    const int py = __float2int_rn(qy);
    const bool v = (px >= 0) & (py >= 0) & (px < FW) & (py < FH) & (cz > 0.0f);

    float4 r0 = {0,0,0,0}, r1 = {0,0,0,0}, r2 = {0,0,0,0}, r3 = {0,0,0,0};
    float4 r4 = {0,0,0,0}, r5 = {0,0,0,0}, r6 = {0,0,0,0}, r7 = {0,0,0,0};
    if (v) {
        const int idx = py * FW + px;
        const float4* row = (const float4*)(T + ((size_t)b * FHW + idx) * NC);
        r0 = row[0]; r1 = row[1]; r2 = row[2]; r3 = row[3];
        r4 = row[4]; r5 = row[5]; r6 = row[6]; r7 = row[7];
    }
    float* ob = out + (size_t)b * NC * NVOX + n;
    const float4 rr[8] = {r0,r1,r2,r3,r4,r5,r6,r7};
    #pragma unroll
    for (int t = 0; t < 8; ++t) {
        ob[(size_t)(4*t + 0) * NVOX] = rr[t].x;
        ob[(size_t)(4*t + 1) * NVOX] = rr[t].y;
        ob[(size_t)(4*t + 2) * NVOX] = rr[t].z;
        ob[(size_t)(4*t + 3) * NVOX] = rr[t].w;
    }
    out[(size_t)NB * NC * NVOX + (size_t)b * NVOX + n] = v ? 1.0f : 0.0f;
}

extern "C" void kernel_launch(void* const* d_in, const int* in_sizes, int n_in,
                              void* d_out, int out_size, void* d_ws, size_t ws_size,
                              hipStream_t stream) {
    const float* proj   = (const float*)d_in[0];
    const float* feat   = (const float*)d_in[1];
    const float* origin = (const float*)d_in[2];
    float* out = (float*)d_out;

    if (ws_size >= IDX_BYTES) {
        int* idxbuf = (int*)d_ws;
        project_kernel<<<(NB * NVOX) / 256, 256, 0, stream>>>(proj, origin, idxbuf, out);
        scatter_kernel<<<(NB * NC * (NVOX / 4)) / 256, 256, 0, stream>>>(feat, idxbuf, out);
    } else {
        float* T = (float*)d_ws;   // R18 fallback (needs 4.9MB)
        transpose_feat_kernel<<<(NB * FHW) / 256, 256, 0, stream>>>(feat, T);
        voxel_backproject_kernel<<<(NB * NVOX) / 256, 256, 0, stream>>>(proj, T, origin, out);
    }
}

// Round 21
// 48.565 us; speedup vs baseline: 1.8960x; 1.8960x over previous
//
#include <hip/hip_runtime.h>
#include <math.h>

#define NX 128
#define NY 128
#define NZ 64
#define NVOX (NX * NY * NZ)   // 1048576 = 1<<20
#define NC 32
#define FH 120
#define FW 160
#define FHW (FH * FW)         // 19200
#define VOXSZ 0.04f
#define NB 2
#define T_BYTES ((size_t)NB * FHW * NC * 4)   // 4,915,200

// Transpose features (B,C,H*W) -> T (B,H*W,C), WIDE: one thread per
// (b, pix, channel-quad). 307200 threads / 1200 blocks (vs 150 before).
__global__ __launch_bounds__(256) void transpose_feat_kernel(
    const float* __restrict__ feat, float* __restrict__ T)
{
    const int t = blockIdx.x * 256 + threadIdx.x;     // 0..307199
    const int quad = t & 7;
    const int pix  = (t >> 3) % FHW;
    const int b    = t / (FHW * 8);
    const float* fb = feat + (size_t)b * NC * FHW + pix;
    float v[4];
    #pragma unroll
    for (int q = 0; q < 4; ++q) v[q] = fb[(size_t)(4 * quad + q) * FHW];
    float4* row = (float4*)(T + ((size_t)b * FHW + pix) * NC);
    row[quad] = make_float4(v[0], v[1], v[2], v[3]);
}

// One thread per voxel (R18 structure), XCD batch-partition swizzle:
// blockIdx%8 in {0..3} -> b=0, {4..7} -> b=1, so each XCD's T working set
// is one batch (2.4MB < 4MB L2).
// Projection = PINNED R14 pipeline (f32, contract off, pairwise association,
// IEEE div, rndne) -- bit-exact. Cached stores (R18-proven).
__global__ __launch_bounds__(256) void voxel_backproject_kernel(
    const float* __restrict__ proj,
    const float* __restrict__ T,
    const float* __restrict__ origin,
    float* __restrict__ out)
{
#pragma clang fp contract(off)
    // de-swizzle: new_bid = q*8 + r; b = r>=4; g = q*4 + (r&3)
    const int q8 = blockIdx.x >> 3;
    const int r8 = blockIdx.x & 7;
    const int b  = r8 >> 2;
    const int g  = q8 * 4 + (r8 & 3);                 // 0..4095 within batch
    const int n  = g * 256 + threadIdx.x;             // voxel id within batch
    const int i = n >> 13;
    const int j = (n >> 6) & (NY - 1);
    const int k = n & (NZ - 1);

    const float* P = proj + b * 12;
    const float ox = origin[b * 3 + 0];
    const float oy = origin[b * 3 + 1];
    const float oz = origin[b * 3 + 2];

    const float wx = (float)i * VOXSZ + ox;
    const float wy = (float)j * VOXSZ + oy;
    const float wz = (float)k * VOXSZ + oz;

    const float tx = P[0] * wx + P[1] * wy;
    const float ty = P[4] * wx + P[5] * wy;
    const float tz = P[8] * wx + P[9] * wy;

    const float cx = tx + (P[2]  * wz + P[3]);
    const float cy = ty + (P[6]  * wz + P[7]);
    const float cz = tz + (P[10] * wz + P[11]);

    const float qx = cx / cz;
    const float qy = cy / cz;
    const int px = __float2int_rn(qx);
    const int py = __float2int_rn(qy);
    const bool v = (px >= 0) & (py >= 0) & (px < FW) & (py < FH) & (cz > 0.0f);

    float4 r0 = {0,0,0,0}, r1 = {0,0,0,0}, r2 = {0,0,0,0}, r3 = {0,0,0,0};
    float4 r4 = {0,0,0,0}, r5 = {0,0,0,0}, r6 = {0,0,0,0}, r7 = {0,0,0,0};
    if (v) {
        const int idx = py * FW + px;
        const float4* row = (const float4*)(T + ((size_t)b * FHW + idx) * NC);
        r0 = row[0]; r1 = row[1]; r2 = row[2]; r3 = row[3];
        r4 = row[4]; r5 = row[5]; r6 = row[6]; r7 = row[7];
    }

    float* ob = out + (size_t)b * NC * NVOX + n;
    const float4 rr[8] = {r0,r1,r2,r3,r4,r5,r6,r7};
    #pragma unroll
    for (int t = 0; t < 8; ++t) {
        ob[(size_t)(4*t + 0) * NVOX] = rr[t].x;
        ob[(size_t)(4*t + 1) * NVOX] = rr[t].y;
        ob[(size_t)(4*t + 2) * NVOX] = rr[t].z;
        ob[(size_t)(4*t + 3) * NVOX] = rr[t].w;
    }
    out[(size_t)NB * NC * NVOX + (size_t)b * NVOX + n] = v ? 1.0f : 0.0f;
}

extern "C" void kernel_launch(void* const* d_in, const int* in_sizes, int n_in,
                              void* d_out, int out_size, void* d_ws, size_t ws_size,
                              hipStream_t stream) {
    const float* proj   = (const float*)d_in[0];
    const float* feat   = (const float*)d_in[1];
    const float* origin = (const float*)d_in[2];
    float* out = (float*)d_out;

    float* T = (float*)d_ws;
    transpose_feat_kernel<<<(NB * FHW * 8) / 256, 256, 0, stream>>>(feat, T);
    const int total = NB * NVOX;                      // 2097152
    voxel_backproject_kernel<<<total / 256, 256, 0, stream>>>(proj, T, origin, out);
}